// Round 1
// baseline (434.904 us; speedup 1.0000x reference)
//
#include <hip/hip_runtime.h>

// out = dequant( int8_gemm( quant(x, in_scale), quant(w, absmax/127) ) + b_q )
// M = 8192, K = 1600, N = 6400.
// R6: LDS XOR swizzle (T2, both-sides-or-neither). Row-major [128][64B] LDS
// tiles put ds_read_b128 lanes (row=..+l15, chunk=quad) at 8 lanes per 4-bank
// slot (8-way conflict, ~2.9x LDS cost -> LDS-bound K-loop). Fix: stage with
// pre-swizzled GLOBAL chunk (chunk ^= (row>>1)&3; LDS dest stays linear as
// global_load_lds requires), read with the same XOR -> 2 lanes/slot (free).
// R5 (kept): XCD-aware swizzle, XCD j owns M-stripe [8j,8j+8), N outer.

#define M_DIM 8192
#define K_DIM 1600
#define N_DIM 6400
#define QMAXF 127.0f

typedef __attribute__((ext_vector_type(4))) int int4v;

// ---------------- ws layout ----------------
// [0, 4)            : uint bits of max|w|  (atomicMax target; memset to 0 each call)
// [256, 256+M*K)    : x_q  int8, row-major [M][K]
// [.. , ..  +N*K)   : wT_q int8, row-major [N][K]  (transposed weight)

__device__ __forceinline__ void load_lds16(const void* gptr, void* lptr) {
    __builtin_amdgcn_global_load_lds((__attribute__((address_space(1))) void*)gptr,
                                     (__attribute__((address_space(3))) void*)lptr,
                                     16, 0, 0);
}

// ---------------- absmax(weight): wave reduce -> LDS -> 1 atomic/block ----------------
__global__ void wmax_kernel(const float* __restrict__ w,
                            unsigned int* __restrict__ wmax_bits, int n4) {
    __shared__ float smax[4];
    const float4* w4 = (const float4*)w;
    int i = blockIdx.x * blockDim.x + threadIdx.x;
    int stride = gridDim.x * blockDim.x;
    float m = 0.0f;
    for (; i < n4; i += stride) {
        float4 v = w4[i];
        m = fmaxf(m, fmaxf(fmaxf(fabsf(v.x), fabsf(v.y)),
                           fmaxf(fabsf(v.z), fabsf(v.w))));
    }
#pragma unroll
    for (int off = 32; off > 0; off >>= 1)
        m = fmaxf(m, __shfl_down(m, off, 64));
    const int wave = threadIdx.x >> 6;
    if ((threadIdx.x & 63) == 0) smax[wave] = m;
    __syncthreads();
    if (threadIdx.x == 0) {
        float mm = fmaxf(fmaxf(smax[0], smax[1]), fmaxf(smax[2], smax[3]));
        atomicMax(wmax_bits, __float_as_uint(mm));  // mm >= 0: uint order == float order
    }
}

// ---------------- quantize x -> int8 [M][K] ----------------
__global__ void quantx_kernel(const float* __restrict__ x, signed char* __restrict__ xq,
                              const float* __restrict__ in_scale_p, int n4) {
    int i = blockIdx.x * blockDim.x + threadIdx.x;
    if (i >= n4) return;
    float s = *in_scale_p;
    float4 v = ((const float4*)x)[i];
    float a = fminf(fmaxf(rintf(v.x / s), -128.0f), 127.0f);
    float b = fminf(fmaxf(rintf(v.y / s), -128.0f), 127.0f);
    float c = fminf(fmaxf(rintf(v.z / s), -128.0f), 127.0f);
    float d = fminf(fmaxf(rintf(v.w / s), -128.0f), 127.0f);
    char4 packed = make_char4((signed char)a, (signed char)b,
                              (signed char)c, (signed char)d);
    ((char4*)xq)[i] = packed;
}

// ---------------- quantize + transpose w -> int8 [N][K], 64x64 tile ----------------
__global__ void quantw_kernel(const float* __restrict__ w, signed char* __restrict__ wT,
                              const unsigned int* __restrict__ wmax_bits) {
    __shared__ signed char tile[64 * 80];  // [n][k], stride 80 keeps 16B alignment
    const float wscale = __uint_as_float(*wmax_bits) / QMAXF;
    const int n0 = blockIdx.x * 64;
    const int k0 = blockIdx.y * 64;
    const int tid = threadIdx.x;
    const int nn = tid & 63;
    const int kb = tid >> 6;  // 0..3
#pragma unroll
    for (int p = 0; p < 16; ++p) {
        const int kk = p * 4 + kb;
        float v = w[(size_t)(k0 + kk) * N_DIM + n0 + nn];  // coalesced along n
        float q = fminf(fmaxf(rintf(v / wscale), -128.0f), 127.0f);
        tile[nn * 80 + kk] = (signed char)q;               // transposed in LDS
    }
    __syncthreads();
    const int n_loc = tid >> 2;
    const int kq = tid & 3;
    int4v val = *(const int4v*)&tile[n_loc * 80 + kq * 16];
    *(int4v*)&wT[(size_t)(n0 + n_loc) * K_DIM + k0 + kq * 16] = val;
}

// ------- int8 GEMM, 128x128 tile, BK=64, dbuf LDS, XCD swizzle, fused epilogue -------
__global__ __launch_bounds__(256, 2) void gemm_i8_kernel(
        const signed char* __restrict__ xq, const signed char* __restrict__ wTq,
        const float* __restrict__ bias, const unsigned int* __restrict__ wmax_bits,
        const float* __restrict__ in_scale_p, const float* __restrict__ out_scale_p,
        float* __restrict__ out) {
    __shared__ signed char A_lds[2][128 * 64];  // 2 x 8 KB  [m][k-chunk swizzled]
    __shared__ signed char B_lds[2][128 * 64];  // 2 x 8 KB  [n][k-chunk swizzled]

    const int tid   = threadIdx.x;
    const int wave  = tid >> 6;
    const int lane  = tid & 63;
    const int quad  = lane >> 4;
    const int l15   = lane & 15;
    const int waveM = wave >> 1;
    const int waveN = wave & 1;

    // XCD-aware swizzle: round-robin dispatch puts gid%8 on XCD gid&7.
    // XCD j owns m-blocks [8j, 8j+8); within an XCD: n outer, m inner.
    const int gid   = blockIdx.x;           // 0..3199
    const int xcd   = gid & 7;
    const int idx   = gid >> 3;             // 0..399
    const int n_blk = idx >> 3;             // 0..49
    const int m_blk = (xcd << 3) | (idx & 7);  // 0..63

    const int blockN0 = n_blk * 128;
    const int blockM0 = m_blk * 128;

    const signed char* Ag = xq  + (size_t)blockM0 * K_DIM;
    const signed char* Bg = wTq + (size_t)blockN0 * K_DIM;

    // Staging: lane i of a wave covers row srow = wave*16 + (i>>2), 16B chunk
    // (i&3) of the 64B row. LDS dest is linear (global_load_lds requirement);
    // the XOR swizzle is applied to the GLOBAL chunk instead:
    //   LDS[row][c] = G[row][c ^ swz(row)],  swz(row) = (row>>1)&3 = (lane>>3)&3.
    const int srow = wave * 16 + (lane >> 2);            // row within 64-row chunk
    const int scol = (((lane & 3) ^ ((lane >> 3) & 3)) * 16);  // swizzled byte col

    int4v acc[4][4];
    const int4v zero4 = {0, 0, 0, 0};
#pragma unroll
    for (int i = 0; i < 4; ++i)
#pragma unroll
        for (int j = 0; j < 4; ++j) acc[i][j] = zero4;

    // ---- prologue: stage tile 0 into buffer 0 ----
#pragma unroll
    for (int t = 0; t < 2; ++t) {
        const int r = t * 64 + srow;
        load_lds16(Ag + (size_t)r * K_DIM + scol, &A_lds[0][(t * 64 + wave * 16) * 64]);
        load_lds16(Bg + (size_t)r * K_DIM + scol, &B_lds[0][(t * 64 + wave * 16) * 64]);
    }

    // Fragment reads: want G[row][quad] = LDS[row][quad ^ swz(row)];
    // row = waveM*64 + mt*16 + l15  ->  swz(row) = (l15>>1)&3  (mt-independent).
    // Within a 16-lane phase (fixed quad) this spreads lanes 2-per-4-bank-slot
    // (conflict-free floor for b128) instead of 8-per-slot.
    const int rchunk = (quad ^ ((l15 >> 1) & 3)) * 16;

    int buf = 0;
    for (int kn = 64; kn <= K_DIM; kn += 64) {  // kn = offset of the NEXT tile
        __syncthreads();

        if (kn < K_DIM) {  // prefetch next tile into alternate buffer
            const int nb = buf ^ 1;
#pragma unroll
            for (int t = 0; t < 2; ++t) {
                const int r = t * 64 + srow;
                load_lds16(Ag + (size_t)r * K_DIM + kn + scol,
                           &A_lds[nb][(t * 64 + wave * 16) * 64]);
                load_lds16(Bg + (size_t)r * K_DIM + kn + scol,
                           &B_lds[nb][(t * 64 + wave * 16) * 64]);
            }
        }

        int4v a[4], b[4];
#pragma unroll
        for (int mt = 0; mt < 4; ++mt)
            a[mt] = *(const int4v*)&A_lds[buf][(waveM * 64 + mt * 16 + l15) * 64 + rchunk];
#pragma unroll
        for (int nt = 0; nt < 4; ++nt)
            b[nt] = *(const int4v*)&B_lds[buf][(waveN * 64 + nt * 16 + l15) * 64 + rchunk];

#pragma unroll
        for (int mt = 0; mt < 4; ++mt)
#pragma unroll
            for (int nt = 0; nt < 4; ++nt)
                acc[mt][nt] = __builtin_amdgcn_mfma_i32_16x16x64_i8(a[mt], b[nt],
                                                                    acc[mt][nt], 0, 0, 0);
        buf ^= 1;
    }

    // epilogue: + b_q, rescale, rint, clip, dequant
    const float s_in  = *in_scale_p;
    const float s_out = *out_scale_p;
    const float wscale = __uint_as_float(*wmax_bits) / QMAXF;
    const float bias_scale = s_in * wscale;
    const float ratio = bias_scale / s_out;

#pragma unroll
    for (int nt = 0; nt < 4; ++nt) {
        const int col = blockN0 + waveN * 64 + nt * 16 + l15;
        const int bq = (int)rintf(bias[col] / bias_scale);
#pragma unroll
        for (int mt = 0; mt < 4; ++mt) {
#pragma unroll
            for (int r = 0; r < 4; ++r) {
                const int row = blockM0 + waveM * 64 + mt * 16 + quad * 4 + r;
                const int av = acc[mt][nt][r] + bq;
                float f = rintf((float)av * ratio);
                f = fminf(fmaxf(f, -128.0f), 127.0f);
                out[(size_t)row * N_DIM + col] = f * s_out;
            }
        }
    }
}

extern "C" void kernel_launch(void* const* d_in, const int* in_sizes, int n_in,
                              void* d_out, int out_size, void* d_ws, size_t ws_size,
                              hipStream_t stream) {
    const float* x         = (const float*)d_in[0];
    const float* w         = (const float*)d_in[1];
    const float* bias      = (const float*)d_in[2];
    const float* in_scale  = (const float*)d_in[3];
    const float* out_scale = (const float*)d_in[4];
    float* out = (float*)d_out;

    unsigned char* ws = (unsigned char*)d_ws;
    unsigned int* wmax_bits = (unsigned int*)ws;
    signed char* xq  = (signed char*)(ws + 256);
    signed char* wTq = (signed char*)(ws + 256 + (size_t)M_DIM * K_DIM);

    hipMemsetAsync(d_ws, 0, 256, stream);

    wmax_kernel<<<320, 256, 0, stream>>>(w, wmax_bits, (K_DIM * N_DIM) / 4);

    quantx_kernel<<<(M_DIM * K_DIM / 4 + 255) / 256, 256, 0, stream>>>(
        x, xq, in_scale, M_DIM * K_DIM / 4);

    dim3 wgrid(N_DIM / 64, K_DIM / 64);  // (100, 25)
    quantw_kernel<<<wgrid, 256, 0, stream>>>(w, wTq, wmax_bits);

    gemm_i8_kernel<<<3200, 256, 0, stream>>>(xq, wTq, bias, wmax_bits,
                                             in_scale, out_scale, out);
}

// Round 2
// 421.141 us; speedup vs baseline: 1.0327x; 1.0327x over previous
//
#include <hip/hip_runtime.h>

// out = dequant( int8_gemm( quant(x, in_scale), quant(w, absmax/127) ) + b_q )
// M = 8192, K = 1600, N = 6400.
// R7: T4 counted-vmcnt pipeline. __syncthreads() emits a full
// "s_waitcnt vmcnt(0) lgkmcnt(0)" before s_barrier -> every K-step drains the
// global_load_lds queue (the m97 ~36% ceiling mechanism, 72% of 2-phase loop
// per m233). Replace with: triple-buffered LDS, prefetch depth 2, raw
// s_barrier + asm "s_waitcnt vmcnt(8)" (tile t's 4 loads done; t+1/t+2's 8
// stay in flight ACROSS the barrier). Tail peeled at vmcnt(4)/vmcnt(0).
// sched_barrier(0) pins ds_reads below entry barrier / MFMAs above exit
// barrier (rule 18). R6 swizzle kept (now on the critical path). R5 XCD
// swizzle kept.

#define M_DIM 8192
#define K_DIM 1600
#define N_DIM 6400
#define QMAXF 127.0f

typedef __attribute__((ext_vector_type(4))) int int4v;

// ---------------- ws layout ----------------
// [0, 4)            : uint bits of max|w|  (atomicMax target; memset to 0 each call)
// [256, 256+M*K)    : x_q  int8, row-major [M][K]
// [.. , ..  +N*K)   : wT_q int8, row-major [N][K]  (transposed weight)

__device__ __forceinline__ void load_lds16(const void* gptr, void* lptr) {
    __builtin_amdgcn_global_load_lds((__attribute__((address_space(1))) void*)gptr,
                                     (__attribute__((address_space(3))) void*)lptr,
                                     16, 0, 0);
}

// ---------------- absmax(weight): wave reduce -> LDS -> 1 atomic/block ----------------
__global__ void wmax_kernel(const float* __restrict__ w,
                            unsigned int* __restrict__ wmax_bits, int n4) {
    __shared__ float smax[4];
    const float4* w4 = (const float4*)w;
    int i = blockIdx.x * blockDim.x + threadIdx.x;
    int stride = gridDim.x * blockDim.x;
    float m = 0.0f;
    for (; i < n4; i += stride) {
        float4 v = w4[i];
        m = fmaxf(m, fmaxf(fmaxf(fabsf(v.x), fabsf(v.y)),
                           fmaxf(fabsf(v.z), fabsf(v.w))));
    }
#pragma unroll
    for (int off = 32; off > 0; off >>= 1)
        m = fmaxf(m, __shfl_down(m, off, 64));
    const int wave = threadIdx.x >> 6;
    if ((threadIdx.x & 63) == 0) smax[wave] = m;
    __syncthreads();
    if (threadIdx.x == 0) {
        float mm = fmaxf(fmaxf(smax[0], smax[1]), fmaxf(smax[2], smax[3]));
        atomicMax(wmax_bits, __float_as_uint(mm));  // mm >= 0: uint order == float order
    }
}

// ---------------- quantize x -> int8 [M][K] ----------------
__global__ void quantx_kernel(const float* __restrict__ x, signed char* __restrict__ xq,
                              const float* __restrict__ in_scale_p, int n4) {
    int i = blockIdx.x * blockDim.x + threadIdx.x;
    if (i >= n4) return;
    float s = *in_scale_p;
    float4 v = ((const float4*)x)[i];
    float a = fminf(fmaxf(rintf(v.x / s), -128.0f), 127.0f);
    float b = fminf(fmaxf(rintf(v.y / s), -128.0f), 127.0f);
    float c = fminf(fmaxf(rintf(v.z / s), -128.0f), 127.0f);
    float d = fminf(fmaxf(rintf(v.w / s), -128.0f), 127.0f);
    char4 packed = make_char4((signed char)a, (signed char)b,
                              (signed char)c, (signed char)d);
    ((char4*)xq)[i] = packed;
}

// ---------------- quantize + transpose w -> int8 [N][K], 64x64 tile ----------------
__global__ void quantw_kernel(const float* __restrict__ w, signed char* __restrict__ wT,
                              const unsigned int* __restrict__ wmax_bits) {
    __shared__ signed char tile[64 * 80];  // [n][k], stride 80 keeps 16B alignment
    const float wscale = __uint_as_float(*wmax_bits) / QMAXF;
    const int n0 = blockIdx.x * 64;
    const int k0 = blockIdx.y * 64;
    const int tid = threadIdx.x;
    const int nn = tid & 63;
    const int kb = tid >> 6;  // 0..3
#pragma unroll
    for (int p = 0; p < 16; ++p) {
        const int kk = p * 4 + kb;
        float v = w[(size_t)(k0 + kk) * N_DIM + n0 + nn];  // coalesced along n
        float q = fminf(fmaxf(rintf(v / wscale), -128.0f), 127.0f);
        tile[nn * 80 + kk] = (signed char)q;               // transposed in LDS
    }
    __syncthreads();
    const int n_loc = tid >> 2;
    const int kq = tid & 3;
    int4v val = *(const int4v*)&tile[n_loc * 80 + kq * 16];
    *(int4v*)&wT[(size_t)(n0 + n_loc) * K_DIM + k0 + kq * 16] = val;
}

// --- int8 GEMM, 128x128 tile, BK=64, 3-buf LDS, counted vmcnt, fused epilogue ---
__global__ __launch_bounds__(256, 2) void gemm_i8_kernel(
        const signed char* __restrict__ xq, const signed char* __restrict__ wTq,
        const float* __restrict__ bias, const unsigned int* __restrict__ wmax_bits,
        const float* __restrict__ in_scale_p, const float* __restrict__ out_scale_p,
        float* __restrict__ out) {
    __shared__ signed char A_lds[3][128 * 64];  // 3 x 8 KB  [m][k-chunk swizzled]
    __shared__ signed char B_lds[3][128 * 64];  // 3 x 8 KB  [n][k-chunk swizzled]

    const int tid   = threadIdx.x;
    const int wave  = tid >> 6;
    const int lane  = tid & 63;
    const int quad  = lane >> 4;
    const int l15   = lane & 15;
    const int waveM = wave >> 1;
    const int waveN = wave & 1;

    // XCD-aware swizzle: round-robin dispatch puts gid%8 on XCD gid&7.
    // XCD j owns m-blocks [8j, 8j+8); within an XCD: n outer, m inner.
    const int gid   = blockIdx.x;           // 0..3199
    const int xcd   = gid & 7;
    const int idx   = gid >> 3;             // 0..399
    const int n_blk = idx >> 3;             // 0..49
    const int m_blk = (xcd << 3) | (idx & 7);  // 0..63

    const int blockN0 = n_blk * 128;
    const int blockM0 = m_blk * 128;

    const signed char* Ag = xq  + (size_t)blockM0 * K_DIM;
    const signed char* Bg = wTq + (size_t)blockN0 * K_DIM;

    // Staging: lane i covers row srow = wave*16 + (i>>2), 16B chunk (i&3) of the
    // 64B row. LDS dest linear (global_load_lds requirement); XOR swizzle is on
    // the GLOBAL chunk: LDS[row][c] = G[row][c ^ ((row>>1)&3)].
    const int srow = wave * 16 + (lane >> 2);
    const int scol = (((lane & 3) ^ ((lane >> 3) & 3)) * 16);

    int4v acc[4][4];
    const int4v zero4 = {0, 0, 0, 0};
#pragma unroll
    for (int i = 0; i < 4; ++i)
#pragma unroll
        for (int j = 0; j < 4; ++j) acc[i][j] = zero4;

    // Fragment reads: G[row][quad] = LDS[row][quad ^ ((l15>>1)&3)] (mt-indep).
    const int rchunk = (quad ^ ((l15 >> 1) & 3)) * 16;

    const int NT = K_DIM / 64;  // 25 K-tiles

    // stage K-tile kt into LDS buffer sb (4 global_load_lds / thread)
    auto STAGE = [&](int sb, int kt) {
        const int kof = kt * 64;
#pragma unroll
        for (int t = 0; t < 2; ++t) {
            const int r = t * 64 + srow;
            load_lds16(Ag + (size_t)r * K_DIM + kof + scol,
                       &A_lds[sb][(t * 64 + wave * 16) * 64]);
            load_lds16(Bg + (size_t)r * K_DIM + kof + scol,
                       &B_lds[sb][(t * 64 + wave * 16) * 64]);
        }
    };

    auto COMPUTE = [&](int cb) {
        int4v a[4], b[4];
#pragma unroll
        for (int mt = 0; mt < 4; ++mt)
            a[mt] = *(const int4v*)&A_lds[cb][(waveM * 64 + mt * 16 + l15) * 64 + rchunk];
#pragma unroll
        for (int nt = 0; nt < 4; ++nt)
            b[nt] = *(const int4v*)&B_lds[cb][(waveN * 64 + nt * 16 + l15) * 64 + rchunk];
#pragma unroll
        for (int mt = 0; mt < 4; ++mt)
#pragma unroll
            for (int nt = 0; nt < 4; ++nt)
                acc[mt][nt] = __builtin_amdgcn_mfma_i32_16x16x64_i8(a[mt], b[nt],
                                                                    acc[mt][nt], 0, 0, 0);
    };

    // ---- prologue: tiles 0,1 in flight ----
    STAGE(0, 0);
    STAGE(1, 1);

    // ---- main loop: tiles 0..NT-3. Steady-state outstanding after STAGE = 12
    // (tiles t,t+1,t+2 x 4 loads); vmcnt(8) completes tile t only. Barrier has
    // NO drain: per-wave vmcnt(8) before it guarantees every wave's slice of
    // tile t has landed. Exit barrier keeps buf[cb] readable until all waves
    // finish (it is overwritten by STAGE in iteration t+1).
    int cb = 0;  // t % 3
    for (int t = 0; t < NT - 2; ++t) {
        const int sb = (cb == 0) ? 2 : cb - 1;  // (t+2) % 3
        STAGE(sb, t + 2);
        asm volatile("s_waitcnt vmcnt(8)" ::: "memory");
        __builtin_amdgcn_s_barrier();
        __builtin_amdgcn_sched_barrier(0);   // keep ds_reads below the barrier
        COMPUTE(cb);
        asm volatile("s_waitcnt lgkmcnt(0)" ::: "memory");
        __builtin_amdgcn_sched_barrier(0);   // keep MFMAs/reads above exit barrier
        __builtin_amdgcn_s_barrier();
        cb = (cb == 2) ? 0 : cb + 1;
    }

    // ---- tail: tile NT-2 (4 newer loads in flight), then NT-1 ----
    asm volatile("s_waitcnt vmcnt(4)" ::: "memory");
    __builtin_amdgcn_s_barrier();
    __builtin_amdgcn_sched_barrier(0);
    COMPUTE(cb);
    cb = (cb == 2) ? 0 : cb + 1;

    asm volatile("s_waitcnt vmcnt(0)" ::: "memory");
    __builtin_amdgcn_s_barrier();
    __builtin_amdgcn_sched_barrier(0);
    COMPUTE(cb);

    // epilogue: + b_q, rescale, rint, clip, dequant
    const float s_in  = *in_scale_p;
    const float s_out = *out_scale_p;
    const float wscale = __uint_as_float(*wmax_bits) / QMAXF;
    const float bias_scale = s_in * wscale;
    const float ratio = bias_scale / s_out;

#pragma unroll
    for (int nt = 0; nt < 4; ++nt) {
        const int col = blockN0 + waveN * 64 + nt * 16 + l15;
        const int bq = (int)rintf(bias[col] / bias_scale);
#pragma unroll
        for (int mt = 0; mt < 4; ++mt) {
#pragma unroll
            for (int r = 0; r < 4; ++r) {
                const int row = blockM0 + waveM * 64 + mt * 16 + quad * 4 + r;
                const int av = acc[mt][nt][r] + bq;
                float f = rintf((float)av * ratio);
                f = fminf(fmaxf(f, -128.0f), 127.0f);
                out[(size_t)row * N_DIM + col] = f * s_out;
            }
        }
    }
}

extern "C" void kernel_launch(void* const* d_in, const int* in_sizes, int n_in,
                              void* d_out, int out_size, void* d_ws, size_t ws_size,
                              hipStream_t stream) {
    const float* x         = (const float*)d_in[0];
    const float* w         = (const float*)d_in[1];
    const float* bias      = (const float*)d_in[2];
    const float* in_scale  = (const float*)d_in[3];
    const float* out_scale = (const float*)d_in[4];
    float* out = (float*)d_out;

    unsigned char* ws = (unsigned char*)d_ws;
    unsigned int* wmax_bits = (unsigned int*)ws;
    signed char* xq  = (signed char*)(ws + 256);
    signed char* wTq = (signed char*)(ws + 256 + (size_t)M_DIM * K_DIM);

    hipMemsetAsync(d_ws, 0, 256, stream);

    wmax_kernel<<<320, 256, 0, stream>>>(w, wmax_bits, (K_DIM * N_DIM) / 4);

    quantx_kernel<<<(M_DIM * K_DIM / 4 + 255) / 256, 256, 0, stream>>>(
        x, xq, in_scale, M_DIM * K_DIM / 4);

    dim3 wgrid(N_DIM / 64, K_DIM / 64);  // (100, 25)
    quantw_kernel<<<wgrid, 256, 0, stream>>>(w, wTq, wmax_bits);

    gemm_i8_kernel<<<3200, 256, 0, stream>>>(xq, wTq, bias, wmax_bits,
                                             in_scale, out_scale, out);
}

// Round 3
// 414.922 us; speedup vs baseline: 1.0482x; 1.0150x over previous
//
#include <hip/hip_runtime.h>

// out = dequant( int8_gemm( quant(x, in_scale), quant(w, absmax/127) ) + b_q )
// M = 8192, K = 1600, N = 6400.
// R8: occupancy 2->3 blocks/CU. Inherited __launch_bounds__(256,2) pinned the
// gemm at 2 waves/SIMD all session; m132 precedent: 3->2 blocks/CU on this
// structure costs -42% (implicit MFMA/staging overlap needs ~3 blocks/CU).
// That masking explains R6 (T2 swizzle) and R7 (T4 counted vmcnt) both being
// neutral. 3-buffer LDS = 48KB -> 3 blocks/CU = 144KB <= 160KB fits.
// R7 (kept): 3-buf, prefetch depth 2, raw s_barrier + counted vmcnt(8/4/0),
// per-wave lgkmcnt(0) before exit barrier. R6 (kept): XOR chunk swizzle
// (global-source side, LDS linear). R5 (kept): XCD-aware block swizzle.

#define M_DIM 8192
#define K_DIM 1600
#define N_DIM 6400
#define QMAXF 127.0f

typedef __attribute__((ext_vector_type(4))) int int4v;

// ---------------- ws layout ----------------
// [0, 4)            : uint bits of max|w|  (atomicMax target; memset to 0 each call)
// [256, 256+M*K)    : x_q  int8, row-major [M][K]
// [.. , ..  +N*K)   : wT_q int8, row-major [N][K]  (transposed weight)

__device__ __forceinline__ void load_lds16(const void* gptr, void* lptr) {
    __builtin_amdgcn_global_load_lds((__attribute__((address_space(1))) void*)gptr,
                                     (__attribute__((address_space(3))) void*)lptr,
                                     16, 0, 0);
}

// ---------------- absmax(weight): wave reduce -> LDS -> 1 atomic/block ----------------
__global__ void wmax_kernel(const float* __restrict__ w,
                            unsigned int* __restrict__ wmax_bits, int n4) {
    __shared__ float smax[4];
    const float4* w4 = (const float4*)w;
    int i = blockIdx.x * blockDim.x + threadIdx.x;
    int stride = gridDim.x * blockDim.x;
    float m = 0.0f;
    for (; i < n4; i += stride) {
        float4 v = w4[i];
        m = fmaxf(m, fmaxf(fmaxf(fabsf(v.x), fabsf(v.y)),
                           fmaxf(fabsf(v.z), fabsf(v.w))));
    }
#pragma unroll
    for (int off = 32; off > 0; off >>= 1)
        m = fmaxf(m, __shfl_down(m, off, 64));
    const int wave = threadIdx.x >> 6;
    if ((threadIdx.x & 63) == 0) smax[wave] = m;
    __syncthreads();
    if (threadIdx.x == 0) {
        float mm = fmaxf(fmaxf(smax[0], smax[1]), fmaxf(smax[2], smax[3]));
        atomicMax(wmax_bits, __float_as_uint(mm));  // mm >= 0: uint order == float order
    }
}

// ---------------- quantize x -> int8 [M][K] ----------------
__global__ void quantx_kernel(const float* __restrict__ x, signed char* __restrict__ xq,
                              const float* __restrict__ in_scale_p, int n4) {
    int i = blockIdx.x * blockDim.x + threadIdx.x;
    if (i >= n4) return;
    float s = *in_scale_p;
    float4 v = ((const float4*)x)[i];
    float a = fminf(fmaxf(rintf(v.x / s), -128.0f), 127.0f);
    float b = fminf(fmaxf(rintf(v.y / s), -128.0f), 127.0f);
    float c = fminf(fmaxf(rintf(v.z / s), -128.0f), 127.0f);
    float d = fminf(fmaxf(rintf(v.w / s), -128.0f), 127.0f);
    char4 packed = make_char4((signed char)a, (signed char)b,
                              (signed char)c, (signed char)d);
    ((char4*)xq)[i] = packed;
}

// ---------------- quantize + transpose w -> int8 [N][K], 64x64 tile ----------------
__global__ void quantw_kernel(const float* __restrict__ w, signed char* __restrict__ wT,
                              const unsigned int* __restrict__ wmax_bits) {
    __shared__ signed char tile[64 * 80];  // [n][k], stride 80 keeps 16B alignment
    const float wscale = __uint_as_float(*wmax_bits) / QMAXF;
    const int n0 = blockIdx.x * 64;
    const int k0 = blockIdx.y * 64;
    const int tid = threadIdx.x;
    const int nn = tid & 63;
    const int kb = tid >> 6;  // 0..3
#pragma unroll
    for (int p = 0; p < 16; ++p) {
        const int kk = p * 4 + kb;
        float v = w[(size_t)(k0 + kk) * N_DIM + n0 + nn];  // coalesced along n
        float q = fminf(fmaxf(rintf(v / wscale), -128.0f), 127.0f);
        tile[nn * 80 + kk] = (signed char)q;               // transposed in LDS
    }
    __syncthreads();
    const int n_loc = tid >> 2;
    const int kq = tid & 3;
    int4v val = *(const int4v*)&tile[n_loc * 80 + kq * 16];
    *(int4v*)&wT[(size_t)(n0 + n_loc) * K_DIM + k0 + kq * 16] = val;
}

// --- int8 GEMM, 128x128 tile, BK=64, 3-buf LDS, counted vmcnt, fused epilogue ---
__global__ __launch_bounds__(256, 3) void gemm_i8_kernel(
        const signed char* __restrict__ xq, const signed char* __restrict__ wTq,
        const float* __restrict__ bias, const unsigned int* __restrict__ wmax_bits,
        const float* __restrict__ in_scale_p, const float* __restrict__ out_scale_p,
        float* __restrict__ out) {
    __shared__ signed char A_lds[3][128 * 64];  // 3 x 8 KB  [m][k-chunk swizzled]
    __shared__ signed char B_lds[3][128 * 64];  // 3 x 8 KB  [n][k-chunk swizzled]

    const int tid   = threadIdx.x;
    const int wave  = tid >> 6;
    const int lane  = tid & 63;
    const int quad  = lane >> 4;
    const int l15   = lane & 15;
    const int waveM = wave >> 1;
    const int waveN = wave & 1;

    // XCD-aware swizzle: round-robin dispatch puts gid%8 on XCD gid&7.
    // XCD j owns m-blocks [8j, 8j+8); within an XCD: n outer, m inner.
    const int gid   = blockIdx.x;           // 0..3199
    const int xcd   = gid & 7;
    const int idx   = gid >> 3;             // 0..399
    const int n_blk = idx >> 3;             // 0..49
    const int m_blk = (xcd << 3) | (idx & 7);  // 0..63

    const int blockN0 = n_blk * 128;
    const int blockM0 = m_blk * 128;

    const signed char* Ag = xq  + (size_t)blockM0 * K_DIM;
    const signed char* Bg = wTq + (size_t)blockN0 * K_DIM;

    // Staging: lane i covers row srow = wave*16 + (i>>2), 16B chunk (i&3) of the
    // 64B row. LDS dest linear (global_load_lds requirement); XOR swizzle is on
    // the GLOBAL chunk: LDS[row][c] = G[row][c ^ ((row>>1)&3)].
    const int srow = wave * 16 + (lane >> 2);
    const int scol = (((lane & 3) ^ ((lane >> 3) & 3)) * 16);

    int4v acc[4][4];
    const int4v zero4 = {0, 0, 0, 0};
#pragma unroll
    for (int i = 0; i < 4; ++i)
#pragma unroll
        for (int j = 0; j < 4; ++j) acc[i][j] = zero4;

    // Fragment reads: G[row][quad] = LDS[row][quad ^ ((l15>>1)&3)] (mt-indep).
    const int rchunk = (quad ^ ((l15 >> 1) & 3)) * 16;

    const int NT = K_DIM / 64;  // 25 K-tiles

    // stage K-tile kt into LDS buffer sb (4 global_load_lds / thread)
    auto STAGE = [&](int sb, int kt) {
        const int kof = kt * 64;
#pragma unroll
        for (int t = 0; t < 2; ++t) {
            const int r = t * 64 + srow;
            load_lds16(Ag + (size_t)r * K_DIM + kof + scol,
                       &A_lds[sb][(t * 64 + wave * 16) * 64]);
            load_lds16(Bg + (size_t)r * K_DIM + kof + scol,
                       &B_lds[sb][(t * 64 + wave * 16) * 64]);
        }
    };

    auto COMPUTE = [&](int cb) {
        int4v a[4], b[4];
#pragma unroll
        for (int mt = 0; mt < 4; ++mt)
            a[mt] = *(const int4v*)&A_lds[cb][(waveM * 64 + mt * 16 + l15) * 64 + rchunk];
#pragma unroll
        for (int nt = 0; nt < 4; ++nt)
            b[nt] = *(const int4v*)&B_lds[cb][(waveN * 64 + nt * 16 + l15) * 64 + rchunk];
#pragma unroll
        for (int mt = 0; mt < 4; ++mt)
#pragma unroll
            for (int nt = 0; nt < 4; ++nt)
                acc[mt][nt] = __builtin_amdgcn_mfma_i32_16x16x64_i8(a[mt], b[nt],
                                                                    acc[mt][nt], 0, 0, 0);
    };

    // ---- prologue: tiles 0,1 in flight ----
    STAGE(0, 0);
    STAGE(1, 1);

    // ---- main loop: tiles 0..NT-3. Steady-state outstanding after STAGE = 12
    // (tiles t,t+1,t+2 x 4 loads); vmcnt(8) completes tile t only. Barrier has
    // NO drain: per-wave vmcnt(8) before it guarantees every wave's slice of
    // tile t has landed. Exit barrier + per-wave lgkmcnt(0) keeps buf[cb]
    // readable until all waves finish (overwritten by STAGE in iteration t+1).
    int cb = 0;  // t % 3
    for (int t = 0; t < NT - 2; ++t) {
        const int sb = (cb == 0) ? 2 : cb - 1;  // (t+2) % 3
        STAGE(sb, t + 2);
        asm volatile("s_waitcnt vmcnt(8)" ::: "memory");
        __builtin_amdgcn_s_barrier();
        __builtin_amdgcn_sched_barrier(0);   // keep ds_reads below the barrier
        COMPUTE(cb);
        asm volatile("s_waitcnt lgkmcnt(0)" ::: "memory");
        __builtin_amdgcn_sched_barrier(0);   // keep MFMAs/reads above exit barrier
        __builtin_amdgcn_s_barrier();
        cb = (cb == 2) ? 0 : cb + 1;
    }

    // ---- tail: tile NT-2 (4 newer loads in flight), then NT-1 ----
    asm volatile("s_waitcnt vmcnt(4)" ::: "memory");
    __builtin_amdgcn_s_barrier();
    __builtin_amdgcn_sched_barrier(0);
    COMPUTE(cb);
    cb = (cb == 2) ? 0 : cb + 1;

    asm volatile("s_waitcnt vmcnt(0)" ::: "memory");
    __builtin_amdgcn_s_barrier();
    __builtin_amdgcn_sched_barrier(0);
    COMPUTE(cb);

    // epilogue: + b_q, rescale, rint, clip, dequant
    const float s_in  = *in_scale_p;
    const float s_out = *out_scale_p;
    const float wscale = __uint_as_float(*wmax_bits) / QMAXF;
    const float bias_scale = s_in * wscale;
    const float ratio = bias_scale / s_out;

#pragma unroll
    for (int nt = 0; nt < 4; ++nt) {
        const int col = blockN0 + waveN * 64 + nt * 16 + l15;
        const int bq = (int)rintf(bias[col] / bias_scale);
#pragma unroll
        for (int mt = 0; mt < 4; ++mt) {
#pragma unroll
            for (int r = 0; r < 4; ++r) {
                const int row = blockM0 + waveM * 64 + mt * 16 + quad * 4 + r;
                const int av = acc[mt][nt][r] + bq;
                float f = rintf((float)av * ratio);
                f = fminf(fmaxf(f, -128.0f), 127.0f);
                out[(size_t)row * N_DIM + col] = f * s_out;
            }
        }
    }
}

extern "C" void kernel_launch(void* const* d_in, const int* in_sizes, int n_in,
                              void* d_out, int out_size, void* d_ws, size_t ws_size,
                              hipStream_t stream) {
    const float* x         = (const float*)d_in[0];
    const float* w         = (const float*)d_in[1];
    const float* bias      = (const float*)d_in[2];
    const float* in_scale  = (const float*)d_in[3];
    const float* out_scale = (const float*)d_in[4];
    float* out = (float*)d_out;

    unsigned char* ws = (unsigned char*)d_ws;
    unsigned int* wmax_bits = (unsigned int*)ws;
    signed char* xq  = (signed char*)(ws + 256);
    signed char* wTq = (signed char*)(ws + 256 + (size_t)M_DIM * K_DIM);

    hipMemsetAsync(d_ws, 0, 256, stream);

    wmax_kernel<<<320, 256, 0, stream>>>(w, wmax_bits, (K_DIM * N_DIM) / 4);

    quantx_kernel<<<(M_DIM * K_DIM / 4 + 255) / 256, 256, 0, stream>>>(
        x, xq, in_scale, M_DIM * K_DIM / 4);

    dim3 wgrid(N_DIM / 64, K_DIM / 64);  // (100, 25)
    quantw_kernel<<<wgrid, 256, 0, stream>>>(w, wTq, wmax_bits);

    gemm_i8_kernel<<<3200, 256, 0, stream>>>(xq, wTq, bias, wmax_bits,
                                             in_scale, out_scale, out);
}

// Round 4
// 396.528 us; speedup vs baseline: 1.0968x; 1.0464x over previous
//
#include <hip/hip_runtime.h>

// out = dequant( int8_gemm( quant(x, in_scale), quant(w, absmax/127) ) + b_q )
// M = 8192, K = 1600, N = 6400.
// R9: non-temporal output stores. Evidence: gemm FETCH_SIZE ~235MB vs 23MB of
// int8 inputs (10x HBM over-fetch, R5 profile) + 210MB mandatory out writes
// => gemm runs at ~84% achievable HBM BW: it is HBM-BOUND on over-fetch.
// Mechanism: the 210MB f32 write stream allocates through L2/L3 and evicts
// A/B, leaking ~212MB of re-fetch. Out is write-once/never-read ->
// __builtin_nontemporal_store (global_store nt) stops the eviction.
// This also explains why R6 (LDS swizzle), R7 (counted vmcnt), R8 (occupancy)
// were ALL neutral: they change cycles, not bytes.
// Kept: R8 3 blocks/CU, R7 3-buf counted-vmcnt pipeline, R6 XOR chunk
// swizzle, R5 XCD-aware block swizzle.

#define M_DIM 8192
#define K_DIM 1600
#define N_DIM 6400
#define QMAXF 127.0f

typedef __attribute__((ext_vector_type(4))) int int4v;

// ---------------- ws layout ----------------
// [0, 4)            : uint bits of max|w|  (atomicMax target; memset to 0 each call)
// [256, 256+M*K)    : x_q  int8, row-major [M][K]
// [.. , ..  +N*K)   : wT_q int8, row-major [N][K]  (transposed weight)

__device__ __forceinline__ void load_lds16(const void* gptr, void* lptr) {
    __builtin_amdgcn_global_load_lds((__attribute__((address_space(1))) void*)gptr,
                                     (__attribute__((address_space(3))) void*)lptr,
                                     16, 0, 0);
}

// ---------------- absmax(weight): wave reduce -> LDS -> 1 atomic/block ----------------
__global__ void wmax_kernel(const float* __restrict__ w,
                            unsigned int* __restrict__ wmax_bits, int n4) {
    __shared__ float smax[4];
    const float4* w4 = (const float4*)w;
    int i = blockIdx.x * blockDim.x + threadIdx.x;
    int stride = gridDim.x * blockDim.x;
    float m = 0.0f;
    for (; i < n4; i += stride) {
        float4 v = w4[i];
        m = fmaxf(m, fmaxf(fmaxf(fabsf(v.x), fabsf(v.y)),
                           fmaxf(fabsf(v.z), fabsf(v.w))));
    }
#pragma unroll
    for (int off = 32; off > 0; off >>= 1)
        m = fmaxf(m, __shfl_down(m, off, 64));
    const int wave = threadIdx.x >> 6;
    if ((threadIdx.x & 63) == 0) smax[wave] = m;
    __syncthreads();
    if (threadIdx.x == 0) {
        float mm = fmaxf(fmaxf(smax[0], smax[1]), fmaxf(smax[2], smax[3]));
        atomicMax(wmax_bits, __float_as_uint(mm));  // mm >= 0: uint order == float order
    }
}

// ---------------- quantize x -> int8 [M][K] ----------------
__global__ void quantx_kernel(const float* __restrict__ x, signed char* __restrict__ xq,
                              const float* __restrict__ in_scale_p, int n4) {
    int i = blockIdx.x * blockDim.x + threadIdx.x;
    if (i >= n4) return;
    float s = *in_scale_p;
    float4 v = ((const float4*)x)[i];
    float a = fminf(fmaxf(rintf(v.x / s), -128.0f), 127.0f);
    float b = fminf(fmaxf(rintf(v.y / s), -128.0f), 127.0f);
    float c = fminf(fmaxf(rintf(v.z / s), -128.0f), 127.0f);
    float d = fminf(fmaxf(rintf(v.w / s), -128.0f), 127.0f);
    char4 packed = make_char4((signed char)a, (signed char)b,
                              (signed char)c, (signed char)d);
    ((char4*)xq)[i] = packed;
}

// ---------------- quantize + transpose w -> int8 [N][K], 64x64 tile ----------------
__global__ void quantw_kernel(const float* __restrict__ w, signed char* __restrict__ wT,
                              const unsigned int* __restrict__ wmax_bits) {
    __shared__ signed char tile[64 * 80];  // [n][k], stride 80 keeps 16B alignment
    const float wscale = __uint_as_float(*wmax_bits) / QMAXF;
    const int n0 = blockIdx.x * 64;
    const int k0 = blockIdx.y * 64;
    const int tid = threadIdx.x;
    const int nn = tid & 63;
    const int kb = tid >> 6;  // 0..3
#pragma unroll
    for (int p = 0; p < 16; ++p) {
        const int kk = p * 4 + kb;
        float v = w[(size_t)(k0 + kk) * N_DIM + n0 + nn];  // coalesced along n
        float q = fminf(fmaxf(rintf(v / wscale), -128.0f), 127.0f);
        tile[nn * 80 + kk] = (signed char)q;               // transposed in LDS
    }
    __syncthreads();
    const int n_loc = tid >> 2;
    const int kq = tid & 3;
    int4v val = *(const int4v*)&tile[n_loc * 80 + kq * 16];
    *(int4v*)&wT[(size_t)(n0 + n_loc) * K_DIM + k0 + kq * 16] = val;
}

// --- int8 GEMM, 128x128 tile, BK=64, 3-buf LDS, counted vmcnt, fused epilogue ---
__global__ __launch_bounds__(256, 3) void gemm_i8_kernel(
        const signed char* __restrict__ xq, const signed char* __restrict__ wTq,
        const float* __restrict__ bias, const unsigned int* __restrict__ wmax_bits,
        const float* __restrict__ in_scale_p, const float* __restrict__ out_scale_p,
        float* __restrict__ out) {
    __shared__ signed char A_lds[3][128 * 64];  // 3 x 8 KB  [m][k-chunk swizzled]
    __shared__ signed char B_lds[3][128 * 64];  // 3 x 8 KB  [n][k-chunk swizzled]

    const int tid   = threadIdx.x;
    const int wave  = tid >> 6;
    const int lane  = tid & 63;
    const int quad  = lane >> 4;
    const int l15   = lane & 15;
    const int waveM = wave >> 1;
    const int waveN = wave & 1;

    // XCD-aware swizzle: round-robin dispatch puts gid%8 on XCD gid&7.
    // XCD j owns m-blocks [8j, 8j+8); within an XCD: n outer, m inner.
    const int gid   = blockIdx.x;           // 0..3199
    const int xcd   = gid & 7;
    const int idx   = gid >> 3;             // 0..399
    const int n_blk = idx >> 3;             // 0..49
    const int m_blk = (xcd << 3) | (idx & 7);  // 0..63

    const int blockN0 = n_blk * 128;
    const int blockM0 = m_blk * 128;

    const signed char* Ag = xq  + (size_t)blockM0 * K_DIM;
    const signed char* Bg = wTq + (size_t)blockN0 * K_DIM;

    // Staging: lane i covers row srow = wave*16 + (i>>2), 16B chunk (i&3) of the
    // 64B row. LDS dest linear (global_load_lds requirement); XOR swizzle is on
    // the GLOBAL chunk: LDS[row][c] = G[row][c ^ ((row>>1)&3)].
    const int srow = wave * 16 + (lane >> 2);
    const int scol = (((lane & 3) ^ ((lane >> 3) & 3)) * 16);

    int4v acc[4][4];
    const int4v zero4 = {0, 0, 0, 0};
#pragma unroll
    for (int i = 0; i < 4; ++i)
#pragma unroll
        for (int j = 0; j < 4; ++j) acc[i][j] = zero4;

    // Fragment reads: G[row][quad] = LDS[row][quad ^ ((l15>>1)&3)] (mt-indep).
    const int rchunk = (quad ^ ((l15 >> 1) & 3)) * 16;

    const int NT = K_DIM / 64;  // 25 K-tiles

    // stage K-tile kt into LDS buffer sb (4 global_load_lds / thread)
    auto STAGE = [&](int sb, int kt) {
        const int kof = kt * 64;
#pragma unroll
        for (int t = 0; t < 2; ++t) {
            const int r = t * 64 + srow;
            load_lds16(Ag + (size_t)r * K_DIM + kof + scol,
                       &A_lds[sb][(t * 64 + wave * 16) * 64]);
            load_lds16(Bg + (size_t)r * K_DIM + kof + scol,
                       &B_lds[sb][(t * 64 + wave * 16) * 64]);
        }
    };

    auto COMPUTE = [&](int cb) {
        int4v a[4], b[4];
#pragma unroll
        for (int mt = 0; mt < 4; ++mt)
            a[mt] = *(const int4v*)&A_lds[cb][(waveM * 64 + mt * 16 + l15) * 64 + rchunk];
#pragma unroll
        for (int nt = 0; nt < 4; ++nt)
            b[nt] = *(const int4v*)&B_lds[cb][(waveN * 64 + nt * 16 + l15) * 64 + rchunk];
#pragma unroll
        for (int mt = 0; mt < 4; ++mt)
#pragma unroll
            for (int nt = 0; nt < 4; ++nt)
                acc[mt][nt] = __builtin_amdgcn_mfma_i32_16x16x64_i8(a[mt], b[nt],
                                                                    acc[mt][nt], 0, 0, 0);
    };

    // ---- prologue: tiles 0,1 in flight ----
    STAGE(0, 0);
    STAGE(1, 1);

    // ---- main loop: tiles 0..NT-3. Steady-state outstanding after STAGE = 12
    // (tiles t,t+1,t+2 x 4 loads); vmcnt(8) completes tile t only. Barrier has
    // NO drain: per-wave vmcnt(8) before it guarantees every wave's slice of
    // tile t has landed. Exit barrier + per-wave lgkmcnt(0) keeps buf[cb]
    // readable until all waves finish (overwritten by STAGE in iteration t+1).
    int cb = 0;  // t % 3
    for (int t = 0; t < NT - 2; ++t) {
        const int sb = (cb == 0) ? 2 : cb - 1;  // (t+2) % 3
        STAGE(sb, t + 2);
        asm volatile("s_waitcnt vmcnt(8)" ::: "memory");
        __builtin_amdgcn_s_barrier();
        __builtin_amdgcn_sched_barrier(0);   // keep ds_reads below the barrier
        COMPUTE(cb);
        asm volatile("s_waitcnt lgkmcnt(0)" ::: "memory");
        __builtin_amdgcn_sched_barrier(0);   // keep MFMAs/reads above exit barrier
        __builtin_amdgcn_s_barrier();
        cb = (cb == 2) ? 0 : cb + 1;
    }

    // ---- tail: tile NT-2 (4 newer loads in flight), then NT-1 ----
    asm volatile("s_waitcnt vmcnt(4)" ::: "memory");
    __builtin_amdgcn_s_barrier();
    __builtin_amdgcn_sched_barrier(0);
    COMPUTE(cb);
    cb = (cb == 2) ? 0 : cb + 1;

    asm volatile("s_waitcnt vmcnt(0)" ::: "memory");
    __builtin_amdgcn_s_barrier();
    __builtin_amdgcn_sched_barrier(0);
    COMPUTE(cb);

    // epilogue: + b_q, rescale, rint, clip, dequant.
    // Out is write-once/never-read: nontemporal stores keep the 210MB write
    // stream from evicting A/B out of L2/L3 (the over-fetch mechanism).
    const float s_in  = *in_scale_p;
    const float s_out = *out_scale_p;
    const float wscale = __uint_as_float(*wmax_bits) / QMAXF;
    const float bias_scale = s_in * wscale;
    const float ratio = bias_scale / s_out;

#pragma unroll
    for (int nt = 0; nt < 4; ++nt) {
        const int col = blockN0 + waveN * 64 + nt * 16 + l15;
        const int bq = (int)rintf(bias[col] / bias_scale);
#pragma unroll
        for (int mt = 0; mt < 4; ++mt) {
#pragma unroll
            for (int r = 0; r < 4; ++r) {
                const int row = blockM0 + waveM * 64 + mt * 16 + quad * 4 + r;
                const int av = acc[mt][nt][r] + bq;
                float f = rintf((float)av * ratio);
                f = fminf(fmaxf(f, -128.0f), 127.0f);
                __builtin_nontemporal_store(f * s_out, &out[(size_t)row * N_DIM + col]);
            }
        }
    }
}

extern "C" void kernel_launch(void* const* d_in, const int* in_sizes, int n_in,
                              void* d_out, int out_size, void* d_ws, size_t ws_size,
                              hipStream_t stream) {
    const float* x         = (const float*)d_in[0];
    const float* w         = (const float*)d_in[1];
    const float* bias      = (const float*)d_in[2];
    const float* in_scale  = (const float*)d_in[3];
    const float* out_scale = (const float*)d_in[4];
    float* out = (float*)d_out;

    unsigned char* ws = (unsigned char*)d_ws;
    unsigned int* wmax_bits = (unsigned int*)ws;
    signed char* xq  = (signed char*)(ws + 256);
    signed char* wTq = (signed char*)(ws + 256 + (size_t)M_DIM * K_DIM);

    hipMemsetAsync(d_ws, 0, 256, stream);

    wmax_kernel<<<320, 256, 0, stream>>>(w, wmax_bits, (K_DIM * N_DIM) / 4);

    quantx_kernel<<<(M_DIM * K_DIM / 4 + 255) / 256, 256, 0, stream>>>(
        x, xq, in_scale, M_DIM * K_DIM / 4);

    dim3 wgrid(N_DIM / 64, K_DIM / 64);  // (100, 25)
    quantw_kernel<<<wgrid, 256, 0, stream>>>(w, wTq, wmax_bits);

    gemm_i8_kernel<<<3200, 256, 0, stream>>>(xq, wTq, bias, wmax_bits,
                                             in_scale, out_scale, out);
}

// Round 5
// 386.809 us; speedup vs baseline: 1.1243x; 1.0251x over previous
//
#include <hip/hip_runtime.h>

// out = dequant( int8_gemm( quant(x, in_scale), quant(w, absmax/127) ) + b_q )
// M = 8192, K = 1600, N = 6400.
// R10: last-headroom bundle. Budget: ~304us harness poison fills (fixed) +
// ~95us ours (pre ~40 + gemm ~55 vs floors 30 + 47).
//  (1) memset node dropped: quantx (now first) zeroes wmax_bits.
//  (2) quantx widened: 64B loads / 16B stores, grid-stride 2048 blocks.
//  (3) gemm -> mfma_i32_32x32x32_i8 (4404 vs 3944 TOPS ceiling, half the
//      MFMA instructions). Same XOR chunk swizzle works: read chunk
//      (ks*2+hi)^((row>>1)&3) -> 2 lanes/4-bank-slot (conflict-free floor).
//      C/D: col=lane&31, row=(reg&3)+8*(reg>>2)+4*(lane>>5) [m74/m101/m127].
// R9 (kept, the session's one big win): nontemporal out stores -- write
// stream was evicting A/B from L2/L3 (FETCH 235MB->55MB, dur -18us).
// R8 (kept): 3 blocks/CU. R7 (kept): 3-buf counted-vmcnt pipeline.
// R6 (kept): XOR chunk swizzle. R5 (kept): XCD-aware block swizzle.

#define M_DIM 8192
#define K_DIM 1600
#define N_DIM 6400
#define QMAXF 127.0f

typedef __attribute__((ext_vector_type(4))) int int4v;
typedef __attribute__((ext_vector_type(16))) int int16v;

// ---------------- ws layout ----------------
// [0, 4)            : uint bits of max|w|  (zeroed by quantx block 0)
// [256, 256+M*K)    : x_q  int8, row-major [M][K]
// [.. , ..  +N*K)   : wT_q int8, row-major [N][K]  (transposed weight)

__device__ __forceinline__ void load_lds16(const void* gptr, void* lptr) {
    __builtin_amdgcn_global_load_lds((__attribute__((address_space(1))) void*)gptr,
                                     (__attribute__((address_space(3))) void*)lptr,
                                     16, 0, 0);
}

// ------- quantize x -> int8 [M][K]; block 0 also zeroes wmax_bits (runs 1st) -------
__global__ void quantx_kernel(const float* __restrict__ x, signed char* __restrict__ xq,
                              const float* __restrict__ in_scale_p,
                              unsigned int* __restrict__ wmax_bits, int n16) {
    if (blockIdx.x == 0 && threadIdx.x == 0) *wmax_bits = 0u;  // replaces memset node
    const float s = *in_scale_p;
    const float4* x4 = (const float4*)x;
    int i = blockIdx.x * blockDim.x + threadIdx.x;
    const int stride = gridDim.x * blockDim.x;
    for (; i < n16; i += stride) {
        signed char tmp[16];
#pragma unroll
        for (int j = 0; j < 4; ++j) {
            float4 v = x4[(size_t)i * 4 + j];
            tmp[j * 4 + 0] = (signed char)fminf(fmaxf(rintf(v.x / s), -128.0f), 127.0f);
            tmp[j * 4 + 1] = (signed char)fminf(fmaxf(rintf(v.y / s), -128.0f), 127.0f);
            tmp[j * 4 + 2] = (signed char)fminf(fmaxf(rintf(v.z / s), -128.0f), 127.0f);
            tmp[j * 4 + 3] = (signed char)fminf(fmaxf(rintf(v.w / s), -128.0f), 127.0f);
        }
        *(int4v*)&xq[(size_t)i * 16] = *(const int4v*)tmp;
    }
}

// ---------------- absmax(weight): wave reduce -> LDS -> 1 atomic/block ----------------
__global__ void wmax_kernel(const float* __restrict__ w,
                            unsigned int* __restrict__ wmax_bits, int n4) {
    __shared__ float smax[4];
    const float4* w4 = (const float4*)w;
    int i = blockIdx.x * blockDim.x + threadIdx.x;
    int stride = gridDim.x * blockDim.x;
    float m = 0.0f;
    for (; i < n4; i += stride) {
        float4 v = w4[i];
        m = fmaxf(m, fmaxf(fmaxf(fabsf(v.x), fabsf(v.y)),
                           fmaxf(fabsf(v.z), fabsf(v.w))));
    }
#pragma unroll
    for (int off = 32; off > 0; off >>= 1)
        m = fmaxf(m, __shfl_down(m, off, 64));
    const int wave = threadIdx.x >> 6;
    if ((threadIdx.x & 63) == 0) smax[wave] = m;
    __syncthreads();
    if (threadIdx.x == 0) {
        float mm = fmaxf(fmaxf(smax[0], smax[1]), fmaxf(smax[2], smax[3]));
        atomicMax(wmax_bits, __float_as_uint(mm));  // mm >= 0: uint order == float order
    }
}

// ---------------- quantize + transpose w -> int8 [N][K], 64x64 tile ----------------
__global__ void quantw_kernel(const float* __restrict__ w, signed char* __restrict__ wT,
                              const unsigned int* __restrict__ wmax_bits) {
    __shared__ signed char tile[64 * 80];  // [n][k], stride 80 keeps 16B alignment
    const float wscale = __uint_as_float(*wmax_bits) / QMAXF;
    const int n0 = blockIdx.x * 64;
    const int k0 = blockIdx.y * 64;
    const int tid = threadIdx.x;
    const int nn = tid & 63;
    const int kb = tid >> 6;  // 0..3
#pragma unroll
    for (int p = 0; p < 16; ++p) {
        const int kk = p * 4 + kb;
        float v = w[(size_t)(k0 + kk) * N_DIM + n0 + nn];  // coalesced along n
        float q = fminf(fmaxf(rintf(v / wscale), -128.0f), 127.0f);
        tile[nn * 80 + kk] = (signed char)q;               // transposed in LDS
    }
    __syncthreads();
    const int n_loc = tid >> 2;
    const int kq = tid & 3;
    int4v val = *(const int4v*)&tile[n_loc * 80 + kq * 16];
    *(int4v*)&wT[(size_t)(n0 + n_loc) * K_DIM + k0 + kq * 16] = val;
}

// --- int8 GEMM, 128x128 tile, BK=64, 32x32x32 MFMA, 3-buf counted-vmcnt ---
__global__ __launch_bounds__(256, 3) void gemm_i8_kernel(
        const signed char* __restrict__ xq, const signed char* __restrict__ wTq,
        const float* __restrict__ bias, const unsigned int* __restrict__ wmax_bits,
        const float* __restrict__ in_scale_p, const float* __restrict__ out_scale_p,
        float* __restrict__ out) {
    __shared__ signed char A_lds[3][128 * 64];  // 3 x 8 KB  [m][k-chunk swizzled]
    __shared__ signed char B_lds[3][128 * 64];  // 3 x 8 KB  [n][k-chunk swizzled]

    const int tid   = threadIdx.x;
    const int wave  = tid >> 6;
    const int lane  = tid & 63;
    const int l31   = lane & 31;
    const int hi    = lane >> 5;          // k-half within 32-wide lane group
    const int waveM = wave >> 1;
    const int waveN = wave & 1;

    // XCD-aware swizzle: round-robin dispatch puts gid%8 on XCD gid&7.
    // XCD j owns m-blocks [8j, 8j+8); within an XCD: n outer, m inner.
    const int gid   = blockIdx.x;           // 0..3199
    const int xcd   = gid & 7;
    const int idx   = gid >> 3;             // 0..399
    const int n_blk = idx >> 3;             // 0..49
    const int m_blk = (xcd << 3) | (idx & 7);  // 0..63

    const int blockN0 = n_blk * 128;
    const int blockM0 = m_blk * 128;

    const signed char* Ag = xq  + (size_t)blockM0 * K_DIM;
    const signed char* Bg = wTq + (size_t)blockN0 * K_DIM;

    // Staging: lane i covers row srow = wave*16 + (i>>2), 16B chunk (i&3) of the
    // 64B row. LDS dest linear (global_load_lds requirement); XOR swizzle is on
    // the GLOBAL chunk: LDS[row][c] = G[row][c ^ ((row>>1)&3)].
    const int srow = wave * 16 + (lane >> 2);
    const int scol = (((lane & 3) ^ ((lane >> 3) & 3)) * 16);

    int16v acc[2][2];
#pragma unroll
    for (int mi = 0; mi < 2; ++mi)
#pragma unroll
        for (int ni = 0; ni < 2; ++ni)
#pragma unroll
            for (int r = 0; r < 16; ++r) acc[mi][ni][r] = 0;

    // Fragment reads (32x32x32): lane holds A[row=base+l31][k=ks*32+hi*16 ..+16].
    // Want G[row][ks*2+hi] = LDS[row][(ks*2+hi) ^ ((row>>1)&3)]; base mult of 32
    // -> (row>>1)&3 = (l31>>1)&3. 16-lane phase: 2 lanes/4-bank-slot (free).
    const int rswz = (l31 >> 1) & 3;

    const int NT = K_DIM / 64;  // 25 K-tiles

    // stage K-tile kt into LDS buffer sb (4 global_load_lds / thread)
    auto STAGE = [&](int sb, int kt) {
        const int kof = kt * 64;
#pragma unroll
        for (int t = 0; t < 2; ++t) {
            const int r = t * 64 + srow;
            load_lds16(Ag + (size_t)r * K_DIM + kof + scol,
                       &A_lds[sb][(t * 64 + wave * 16) * 64]);
            load_lds16(Bg + (size_t)r * K_DIM + kof + scol,
                       &B_lds[sb][(t * 64 + wave * 16) * 64]);
        }
    };

    auto COMPUTE = [&](int cb) {
        int4v a[2][2], b[2][2];  // [ks][tile]
#pragma unroll
        for (int ks = 0; ks < 2; ++ks)
#pragma unroll
            for (int ti = 0; ti < 2; ++ti) {
                const int ch = ((((ks << 1) | hi) ^ rswz) << 4);
                a[ks][ti] = *(const int4v*)
                    &A_lds[cb][(waveM * 64 + ti * 32 + l31) * 64 + ch];
                b[ks][ti] = *(const int4v*)
                    &B_lds[cb][(waveN * 64 + ti * 32 + l31) * 64 + ch];
            }
#pragma unroll
        for (int ks = 0; ks < 2; ++ks)
#pragma unroll
            for (int mi = 0; mi < 2; ++mi)
#pragma unroll
                for (int ni = 0; ni < 2; ++ni)
                    acc[mi][ni] = __builtin_amdgcn_mfma_i32_32x32x32_i8(
                        a[ks][mi], b[ks][ni], acc[mi][ni], 0, 0, 0);
    };

    // ---- prologue: tiles 0,1 in flight ----
    STAGE(0, 0);
    STAGE(1, 1);

    // ---- main loop: tiles 0..NT-3. Steady-state outstanding after STAGE = 12
    // (tiles t,t+1,t+2 x 4 loads); vmcnt(8) completes tile t only. Barrier has
    // NO drain: per-wave vmcnt(8) before it guarantees every wave's slice of
    // tile t has landed. Exit barrier + per-wave lgkmcnt(0) keeps buf[cb]
    // readable until all waves finish (overwritten by STAGE in iteration t+1).
    int cb = 0;  // t % 3
    for (int t = 0; t < NT - 2; ++t) {
        const int sb = (cb == 0) ? 2 : cb - 1;  // (t+2) % 3
        STAGE(sb, t + 2);
        asm volatile("s_waitcnt vmcnt(8)" ::: "memory");
        __builtin_amdgcn_s_barrier();
        __builtin_amdgcn_sched_barrier(0);   // keep ds_reads below the barrier
        COMPUTE(cb);
        asm volatile("s_waitcnt lgkmcnt(0)" ::: "memory");
        __builtin_amdgcn_sched_barrier(0);   // keep MFMAs/reads above exit barrier
        __builtin_amdgcn_s_barrier();
        cb = (cb == 2) ? 0 : cb + 1;
    }

    // ---- tail: tile NT-2 (4 newer loads in flight), then NT-1 ----
    asm volatile("s_waitcnt vmcnt(4)" ::: "memory");
    __builtin_amdgcn_s_barrier();
    __builtin_amdgcn_sched_barrier(0);
    COMPUTE(cb);
    cb = (cb == 2) ? 0 : cb + 1;

    asm volatile("s_waitcnt vmcnt(0)" ::: "memory");
    __builtin_amdgcn_s_barrier();
    __builtin_amdgcn_sched_barrier(0);
    COMPUTE(cb);

    // epilogue: + b_q, rescale, rint, clip, dequant.
    // 32x32 C/D: col = lane&31 (N), row_m = (reg&3) + 8*(reg>>2) + 4*hi.
    // Nontemporal stores: write-once stream must not evict A/B from L2/L3.
    const float s_in  = *in_scale_p;
    const float s_out = *out_scale_p;
    const float wscale = __uint_as_float(*wmax_bits) / QMAXF;
    const float bias_scale = s_in * wscale;
    const float ratio = bias_scale / s_out;

#pragma unroll
    for (int ni = 0; ni < 2; ++ni) {
        const int col = blockN0 + waveN * 64 + ni * 32 + l31;
        const int bq = (int)rintf(bias[col] / bias_scale);
#pragma unroll
        for (int mi = 0; mi < 2; ++mi) {
#pragma unroll
            for (int reg = 0; reg < 16; ++reg) {
                const int row = blockM0 + waveM * 64 + mi * 32 +
                                (reg & 3) + 8 * (reg >> 2) + 4 * hi;
                const int av = acc[mi][ni][reg] + bq;
                float f = rintf((float)av * ratio);
                f = fminf(fmaxf(f, -128.0f), 127.0f);
                __builtin_nontemporal_store(f * s_out, &out[(size_t)row * N_DIM + col]);
            }
        }
    }
}

extern "C" void kernel_launch(void* const* d_in, const int* in_sizes, int n_in,
                              void* d_out, int out_size, void* d_ws, size_t ws_size,
                              hipStream_t stream) {
    const float* x         = (const float*)d_in[0];
    const float* w         = (const float*)d_in[1];
    const float* bias      = (const float*)d_in[2];
    const float* in_scale  = (const float*)d_in[3];
    const float* out_scale = (const float*)d_in[4];
    float* out = (float*)d_out;

    unsigned char* ws = (unsigned char*)d_ws;
    unsigned int* wmax_bits = (unsigned int*)ws;
    signed char* xq  = (signed char*)(ws + 256);
    signed char* wTq = (signed char*)(ws + 256 + (size_t)M_DIM * K_DIM);

    // quantx first: zeroes wmax_bits (stream order covers wmax's atomics),
    // no separate memset node.
    quantx_kernel<<<2048, 256, 0, stream>>>(x, xq, in_scale, wmax_bits,
                                            M_DIM * K_DIM / 16);

    wmax_kernel<<<320, 256, 0, stream>>>(w, wmax_bits, (K_DIM * N_DIM) / 4);

    dim3 wgrid(N_DIM / 64, K_DIM / 64);  // (100, 25)
    quantw_kernel<<<wgrid, 256, 0, stream>>>(w, wTq, wmax_bits);

    gemm_i8_kernel<<<3200, 256, 0, stream>>>(xq, wTq, bias, wmax_bits,
                                             in_scale, out_scale, out);
}

// Round 6
// 384.647 us; speedup vs baseline: 1.1307x; 1.0056x over previous
//
#include <hip/hip_runtime.h>

// out = dequant( int8_gemm( quant(x, in_scale), quant(w, absmax/127) ) + b_q )
// M = 8192, K = 1600, N = 6400.
// R11: fix 32x32 fragment-read bank conflicts. R10 introduced
// SQ_LDS_BANK_CONFLICT 0 -> 1.02e7: rswz=(l31>>1)&3 has period 8 in row, so
// lanes {l,l+8,l+16,l+24} share a 4-bank slot (4-way, ~1.58x). New swizzle
// swz(row) = ((row>>1)^(row>>3))&3 has period 32: those 4 lanes now hit 4
// distinct slots; contiguous 8-lane groups keep the full-permutation property
// (rows 0-7 unchanged). Both sides updated together (rule 21):
//   stage: global chunk (lane&3)^sswz, sswz=((lane>>3)&3)^((2*wave+(lane>>5))&3)
//   read:  chunk (2ks+hi)^rswz,        rswz=((l31>>1)^(l31>>3))&3
// R10 (kept): 32x32x32 MFMA, memset-free, wide quantx. R9 (kept): nt stores
// (FETCH 235->55MB). R8: 3 blocks/CU. R7: 3-buf counted vmcnt. R5: XCD swizzle.

#define M_DIM 8192
#define K_DIM 1600
#define N_DIM 6400
#define QMAXF 127.0f

typedef __attribute__((ext_vector_type(4))) int int4v;
typedef __attribute__((ext_vector_type(16))) int int16v;

// ---------------- ws layout ----------------
// [0, 4)            : uint bits of max|w|  (zeroed by quantx block 0)
// [256, 256+M*K)    : x_q  int8, row-major [M][K]
// [.. , ..  +N*K)   : wT_q int8, row-major [N][K]  (transposed weight)

__device__ __forceinline__ void load_lds16(const void* gptr, void* lptr) {
    __builtin_amdgcn_global_load_lds((__attribute__((address_space(1))) void*)gptr,
                                     (__attribute__((address_space(3))) void*)lptr,
                                     16, 0, 0);
}

// ------- quantize x -> int8 [M][K]; block 0 also zeroes wmax_bits (runs 1st) -------
__global__ void quantx_kernel(const float* __restrict__ x, signed char* __restrict__ xq,
                              const float* __restrict__ in_scale_p,
                              unsigned int* __restrict__ wmax_bits, int n16) {
    if (blockIdx.x == 0 && threadIdx.x == 0) *wmax_bits = 0u;  // replaces memset node
    const float s = *in_scale_p;
    const float4* x4 = (const float4*)x;
    int i = blockIdx.x * blockDim.x + threadIdx.x;
    const int stride = gridDim.x * blockDim.x;
    for (; i < n16; i += stride) {
        signed char tmp[16];
#pragma unroll
        for (int j = 0; j < 4; ++j) {
            float4 v = x4[(size_t)i * 4 + j];
            tmp[j * 4 + 0] = (signed char)fminf(fmaxf(rintf(v.x / s), -128.0f), 127.0f);
            tmp[j * 4 + 1] = (signed char)fminf(fmaxf(rintf(v.y / s), -128.0f), 127.0f);
            tmp[j * 4 + 2] = (signed char)fminf(fmaxf(rintf(v.z / s), -128.0f), 127.0f);
            tmp[j * 4 + 3] = (signed char)fminf(fmaxf(rintf(v.w / s), -128.0f), 127.0f);
        }
        *(int4v*)&xq[(size_t)i * 16] = *(const int4v*)tmp;
    }
}

// ---------------- absmax(weight): wave reduce -> LDS -> 1 atomic/block ----------------
__global__ void wmax_kernel(const float* __restrict__ w,
                            unsigned int* __restrict__ wmax_bits, int n4) {
    __shared__ float smax[4];
    const float4* w4 = (const float4*)w;
    int i = blockIdx.x * blockDim.x + threadIdx.x;
    int stride = gridDim.x * blockDim.x;
    float m = 0.0f;
    for (; i < n4; i += stride) {
        float4 v = w4[i];
        m = fmaxf(m, fmaxf(fmaxf(fabsf(v.x), fabsf(v.y)),
                           fmaxf(fabsf(v.z), fabsf(v.w))));
    }
#pragma unroll
    for (int off = 32; off > 0; off >>= 1)
        m = fmaxf(m, __shfl_down(m, off, 64));
    const int wave = threadIdx.x >> 6;
    if ((threadIdx.x & 63) == 0) smax[wave] = m;
    __syncthreads();
    if (threadIdx.x == 0) {
        float mm = fmaxf(fmaxf(smax[0], smax[1]), fmaxf(smax[2], smax[3]));
        atomicMax(wmax_bits, __float_as_uint(mm));  // mm >= 0: uint order == float order
    }
}

// ---------------- quantize + transpose w -> int8 [N][K], 64x64 tile ----------------
__global__ void quantw_kernel(const float* __restrict__ w, signed char* __restrict__ wT,
                              const unsigned int* __restrict__ wmax_bits) {
    __shared__ signed char tile[64 * 80];  // [n][k], stride 80 keeps 16B alignment
    const float wscale = __uint_as_float(*wmax_bits) / QMAXF;
    const int n0 = blockIdx.x * 64;
    const int k0 = blockIdx.y * 64;
    const int tid = threadIdx.x;
    const int nn = tid & 63;
    const int kb = tid >> 6;  // 0..3
#pragma unroll
    for (int p = 0; p < 16; ++p) {
        const int kk = p * 4 + kb;
        float v = w[(size_t)(k0 + kk) * N_DIM + n0 + nn];  // coalesced along n
        float q = fminf(fmaxf(rintf(v / wscale), -128.0f), 127.0f);
        tile[nn * 80 + kk] = (signed char)q;               // transposed in LDS
    }
    __syncthreads();
    const int n_loc = tid >> 2;
    const int kq = tid & 3;
    int4v val = *(const int4v*)&tile[n_loc * 80 + kq * 16];
    *(int4v*)&wT[(size_t)(n0 + n_loc) * K_DIM + k0 + kq * 16] = val;
}

// --- int8 GEMM, 128x128 tile, BK=64, 32x32x32 MFMA, 3-buf counted-vmcnt ---
__global__ __launch_bounds__(256, 3) void gemm_i8_kernel(
        const signed char* __restrict__ xq, const signed char* __restrict__ wTq,
        const float* __restrict__ bias, const unsigned int* __restrict__ wmax_bits,
        const float* __restrict__ in_scale_p, const float* __restrict__ out_scale_p,
        float* __restrict__ out) {
    __shared__ signed char A_lds[3][128 * 64];  // 3 x 8 KB  [m][k-chunk swizzled]
    __shared__ signed char B_lds[3][128 * 64];  // 3 x 8 KB  [n][k-chunk swizzled]

    const int tid   = threadIdx.x;
    const int wave  = tid >> 6;
    const int lane  = tid & 63;
    const int l31   = lane & 31;
    const int hi    = lane >> 5;          // k-half within 32-wide lane group
    const int waveM = wave >> 1;
    const int waveN = wave & 1;

    // XCD-aware swizzle: round-robin dispatch puts gid%8 on XCD gid&7.
    // XCD j owns m-blocks [8j, 8j+8); within an XCD: n outer, m inner.
    const int gid   = blockIdx.x;           // 0..3199
    const int xcd   = gid & 7;
    const int idx   = gid >> 3;             // 0..399
    const int n_blk = idx >> 3;             // 0..49
    const int m_blk = (xcd << 3) | (idx & 7);  // 0..63

    const int blockN0 = n_blk * 128;
    const int blockM0 = m_blk * 128;

    const signed char* Ag = xq  + (size_t)blockM0 * K_DIM;
    const signed char* Bg = wTq + (size_t)blockN0 * K_DIM;

    // Staging: lane i covers row srow = wave*16 + (i>>2), 16B chunk (i&3) of the
    // 64B row. LDS dest linear (global_load_lds requirement); XOR swizzle on the
    // GLOBAL chunk: LDS[row][c] = G[row][c ^ swz(row)],
    //   swz(row) = ((row>>1) ^ (row>>3)) & 3   (period 32 in row).
    // For srow = wave*16 + (lane>>2) (and srow+64: both terms invariant mod 4):
    //   sswz = ((lane>>3)&3) ^ ((2*wave + (lane>>5)) & 3).
    const int srow = wave * 16 + (lane >> 2);
    const int sswz = (((lane >> 3) & 3) ^ ((2 * wave + (lane >> 5)) & 3));
    const int scol = (((lane & 3) ^ sswz) * 16);

    int16v acc[2][2];
#pragma unroll
    for (int mi = 0; mi < 2; ++mi)
#pragma unroll
        for (int ni = 0; ni < 2; ++ni)
#pragma unroll
            for (int r = 0; r < 16; ++r) acc[mi][ni][r] = 0;

    // Fragment reads (32x32x32): lane reads G[row][2ks+hi] = LDS[row][(2ks+hi)^swz(row)],
    // row = wbase + ti*32 + l31 -> swz(row) = ((l31>>1) ^ (l31>>3)) & 3
    // (wbase, ti*32 terms vanish mod 4). Period-32: lanes {l,l+8,l+16,l+24} now
    // hit 4 distinct bank slots (was 4-way same-slot with period-8 swizzle).
    const int rswz = ((l31 >> 1) ^ (l31 >> 3)) & 3;

    const int NT = K_DIM / 64;  // 25 K-tiles

    // stage K-tile kt into LDS buffer sb (4 global_load_lds / thread)
    auto STAGE = [&](int sb, int kt) {
        const int kof = kt * 64;
#pragma unroll
        for (int t = 0; t < 2; ++t) {
            const int r = t * 64 + srow;
            load_lds16(Ag + (size_t)r * K_DIM + kof + scol,
                       &A_lds[sb][(t * 64 + wave * 16) * 64]);
            load_lds16(Bg + (size_t)r * K_DIM + kof + scol,
                       &B_lds[sb][(t * 64 + wave * 16) * 64]);
        }
    };

    auto COMPUTE = [&](int cb) {
        int4v a[2][2], b[2][2];  // [ks][tile]
#pragma unroll
        for (int ks = 0; ks < 2; ++ks)
#pragma unroll
            for (int ti = 0; ti < 2; ++ti) {
                const int ch = ((((ks << 1) | hi) ^ rswz) << 4);
                a[ks][ti] = *(const int4v*)
                    &A_lds[cb][(waveM * 64 + ti * 32 + l31) * 64 + ch];
                b[ks][ti] = *(const int4v*)
                    &B_lds[cb][(waveN * 64 + ti * 32 + l31) * 64 + ch];
            }
#pragma unroll
        for (int ks = 0; ks < 2; ++ks)
#pragma unroll
            for (int mi = 0; mi < 2; ++mi)
#pragma unroll
                for (int ni = 0; ni < 2; ++ni)
                    acc[mi][ni] = __builtin_amdgcn_mfma_i32_32x32x32_i8(
                        a[ks][mi], b[ks][ni], acc[mi][ni], 0, 0, 0);
    };

    // ---- prologue: tiles 0,1 in flight ----
    STAGE(0, 0);
    STAGE(1, 1);

    // ---- main loop: tiles 0..NT-3. Steady-state outstanding after STAGE = 12
    // (tiles t,t+1,t+2 x 4 loads); vmcnt(8) completes tile t only. Barrier has
    // NO drain: per-wave vmcnt(8) before it guarantees every wave's slice of
    // tile t has landed. Exit barrier + per-wave lgkmcnt(0) keeps buf[cb]
    // readable until all waves finish (overwritten by STAGE in iteration t+1).
    int cb = 0;  // t % 3
    for (int t = 0; t < NT - 2; ++t) {
        const int sb = (cb == 0) ? 2 : cb - 1;  // (t+2) % 3
        STAGE(sb, t + 2);
        asm volatile("s_waitcnt vmcnt(8)" ::: "memory");
        __builtin_amdgcn_s_barrier();
        __builtin_amdgcn_sched_barrier(0);   // keep ds_reads below the barrier
        COMPUTE(cb);
        asm volatile("s_waitcnt lgkmcnt(0)" ::: "memory");
        __builtin_amdgcn_sched_barrier(0);   // keep MFMAs/reads above exit barrier
        __builtin_amdgcn_s_barrier();
        cb = (cb == 2) ? 0 : cb + 1;
    }

    // ---- tail: tile NT-2 (4 newer loads in flight), then NT-1 ----
    asm volatile("s_waitcnt vmcnt(4)" ::: "memory");
    __builtin_amdgcn_s_barrier();
    __builtin_amdgcn_sched_barrier(0);
    COMPUTE(cb);
    cb = (cb == 2) ? 0 : cb + 1;

    asm volatile("s_waitcnt vmcnt(0)" ::: "memory");
    __builtin_amdgcn_s_barrier();
    __builtin_amdgcn_sched_barrier(0);
    COMPUTE(cb);

    // epilogue: + b_q, rescale, rint, clip, dequant.
    // 32x32 C/D: col = lane&31 (N), row_m = (reg&3) + 8*(reg>>2) + 4*hi.
    // Nontemporal stores: write-once stream must not evict A/B from L2/L3.
    const float s_in  = *in_scale_p;
    const float s_out = *out_scale_p;
    const float wscale = __uint_as_float(*wmax_bits) / QMAXF;
    const float bias_scale = s_in * wscale;
    const float ratio = bias_scale / s_out;

#pragma unroll
    for (int ni = 0; ni < 2; ++ni) {
        const int col = blockN0 + waveN * 64 + ni * 32 + l31;
        const int bq = (int)rintf(bias[col] / bias_scale);
#pragma unroll
        for (int mi = 0; mi < 2; ++mi) {
#pragma unroll
            for (int reg = 0; reg < 16; ++reg) {
                const int row = blockM0 + waveM * 64 + mi * 32 +
                                (reg & 3) + 8 * (reg >> 2) + 4 * hi;
                const int av = acc[mi][ni][reg] + bq;
                float f = rintf((float)av * ratio);
                f = fminf(fmaxf(f, -128.0f), 127.0f);
                __builtin_nontemporal_store(f * s_out, &out[(size_t)row * N_DIM + col]);
            }
        }
    }
}

extern "C" void kernel_launch(void* const* d_in, const int* in_sizes, int n_in,
                              void* d_out, int out_size, void* d_ws, size_t ws_size,
                              hipStream_t stream) {
    const float* x         = (const float*)d_in[0];
    const float* w         = (const float*)d_in[1];
    const float* bias      = (const float*)d_in[2];
    const float* in_scale  = (const float*)d_in[3];
    const float* out_scale = (const float*)d_in[4];
    float* out = (float*)d_out;

    unsigned char* ws = (unsigned char*)d_ws;
    unsigned int* wmax_bits = (unsigned int*)ws;
    signed char* xq  = (signed char*)(ws + 256);
    signed char* wTq = (signed char*)(ws + 256 + (size_t)M_DIM * K_DIM);

    // quantx first: zeroes wmax_bits (stream order covers wmax's atomics),
    // no separate memset node.
    quantx_kernel<<<2048, 256, 0, stream>>>(x, xq, in_scale, wmax_bits,
                                            M_DIM * K_DIM / 16);

    wmax_kernel<<<320, 256, 0, stream>>>(w, wmax_bits, (K_DIM * N_DIM) / 4);

    dim3 wgrid(N_DIM / 64, K_DIM / 64);  // (100, 25)
    quantw_kernel<<<wgrid, 256, 0, stream>>>(w, wTq, wmax_bits);

    gemm_i8_kernel<<<3200, 256, 0, stream>>>(xq, wTq, bias, wmax_bits,
                                             in_scale, out_scale, out);
}